// Round 6
// baseline (326.506 us; speedup 1.0000x reference)
//
#include <hip/hip_runtime.h>
#include <hip/hip_bf16.h>
#include <cstdint>
#include <cstddef>

// Problem dims (fixed by the reference)
#define M_DIM 16384
#define IN_F  1024
#define OUT_F 2048
#define K_CAT 2048            // concatenated K = 2*IN_F
#define NT    (K_CAT / 32)    // 64 K-tiles of BK=32

typedef float f32x16 __attribute__((ext_vector_type(16)));
typedef short short8 __attribute__((ext_vector_type(8)));   // 8 bf16 in 4 VGPRs

// async global->LDS, 16B per lane (global_load_lds_dwordx4)
__device__ __forceinline__ void gld_lds16(const void* gptr, void* lptr) {
    __builtin_amdgcn_global_load_lds(
        (const __attribute__((address_space(1))) uint32_t*)gptr,
        (__attribute__((address_space(3))) uint32_t*)lptr,
        16 /*bytes*/, 0 /*offset*/, 0 /*aux*/);
}

// ---------------------------------------------------------------------------
// prep_z: A = [bf16(z*z) | bf16(z)] as (M, 2048) row-major. 8 floats/thread.
// ---------------------------------------------------------------------------
__global__ __launch_bounds__(256) void prep_z_kernel(const float* __restrict__ z,
                                                     __hip_bfloat16* __restrict__ A) {
    const int idx = blockIdx.x * 256 + threadIdx.x;   // 0 .. M*IN_F/8-1
    const int m  = idx >> 7;          // / (IN_F/8)
    const int c8 = (idx & 127) * 8;
    const float4 v0 = ((const float4*)z)[idx * 2];
    const float4 v1 = ((const float4*)z)[idx * 2 + 1];
    const float x[8] = {v0.x, v0.y, v0.z, v0.w, v1.x, v1.y, v1.z, v1.w};
    __hip_bfloat16 q[8], r[8];
#pragma unroll
    for (int j = 0; j < 8; ++j) {
        q[j] = __float2bfloat16(x[j] * x[j]);
        r[j] = __float2bfloat16(x[j]);
    }
    __hip_bfloat16* rowp = A + (size_t)m * K_CAT;
    *(uint4*)&rowp[c8]        = *(uint4*)q;   // z^2 half
    *(uint4*)&rowp[IN_F + c8] = *(uint4*)r;   // z half
}

// ---------------------------------------------------------------------------
// prep_b: B[k,:] = [bf16(-d) | bf16(2*d*mean)]  (OUT_F x 2048, B^T layout)
//         mcm[k] = sum_i d*mean^2 ; ts[k] = tanh(scale[k])
// ---------------------------------------------------------------------------
__global__ __launch_bounds__(256) void prep_b_kernel(const float* __restrict__ diag,
                                                     const float* __restrict__ mean,
                                                     const float* __restrict__ scale,
                                                     __hip_bfloat16* __restrict__ B,
                                                     float* __restrict__ mcm,
                                                     float* __restrict__ ts) {
    const int k = blockIdx.x;
    const int t = threadIdx.x;
    const float4 dp = ((const float4*)(diag + (size_t)k * IN_F))[t];
    const float4 mp = ((const float4*)(mean + (size_t)k * IN_F))[t];
    const float dx[4] = {dp.x, dp.y, dp.z, dp.w};
    const float mx[4] = {mp.x, mp.y, mp.z, mp.w};
    __hip_bfloat16 nb[4], pb[4];
    float acc = 0.f;
#pragma unroll
    for (int j = 0; j < 4; ++j) {
        const float d = 0.1f + 0.9f / (1.f + __expf(-dx[j]));  // sigmoid clamp
        nb[j] = __float2bfloat16(-d);
        pb[j] = __float2bfloat16(2.f * d * mx[j]);
        acc += d * mx[j] * mx[j];
    }
    __hip_bfloat16* rowp = B + (size_t)k * K_CAT;
    *(uint2*)&rowp[t * 4]        = *(uint2*)nb;
    *(uint2*)&rowp[IN_F + t * 4] = *(uint2*)pb;
#pragma unroll
    for (int off = 32; off > 0; off >>= 1) acc += __shfl_down(acc, off);
    __shared__ float red[4];
    if ((t & 63) == 0) red[t >> 6] = acc;
    __syncthreads();
    if (t == 0) {
        mcm[k] = red[0] + red[1] + red[2] + red[3];
        ts[k]  = tanhf(scale[k]);
    }
}

// ---------------------------------------------------------------------------
// gemm_exp: out[m,n] = ts[n] * exp( A(m,:)·B(n,:) - mcm[n] )
// BM=BN=256, BK=32, 8 waves (2M x 4N), per-wave 128x64, mfma 32x32x16.
// 4-deep LDS ring, counted vmcnt(16), ONE barrier per kt, counted lgkmcnt(6)
// splits the kt into two k-slices so ks=1 ds_reads drain under ks=0 MFMAs.
// k-slot XOR swizzle (both sides: pre-swizzled global source + swizzled
// ds_read offset; LDS dest linear for global_load_lds).
// ---------------------------------------------------------------------------
__global__ __launch_bounds__(512, 2) void gemm_exp_kernel(
    const __hip_bfloat16* __restrict__ A,   // M x 2048
    const __hip_bfloat16* __restrict__ B,   // OUT_F x 2048 (B^T)
    const float* __restrict__ mcm,
    const float* __restrict__ ts,
    float* __restrict__ out) {
    __shared__ __align__(16) __hip_bfloat16 smem[4][2][8192];  // 4 bufs x (A,B) x 16KB

    const int t = threadIdx.x;
    // XCD-aware swizzle: nwg=512, 512%8==0 -> simple form is bijective.
    const int wg = ((blockIdx.x & 7) << 6) | (blockIdx.x >> 3);
    const int tn = wg & 7;    // 8 N tiles (consecutive wg share the A panel)
    const int tm = wg >> 3;   // 64 M tiles

    // --- staging: chunk c covers LDS bytes [c*16, c*16+16) ---
    // row = c>>2 (64B rows), LDS 16B-slot u = c&3 holds global k-sub u^((row>>1)&3)
    const int c0 = t, c1 = t + 512;
    const int r0 = c0 >> 2, u0 = c0 & 3;
    const int r1 = c1 >> 2, u1 = c1 & 3;
    const int s0 = u0 ^ ((r0 >> 1) & 3);
    const int s1 = u1 ^ ((r1 >> 1) & 3);
    const __hip_bfloat16* gA0 = A + (size_t)(tm * 256 + r0) * K_CAT + s0 * 8;
    const __hip_bfloat16* gA1 = A + (size_t)(tm * 256 + r1) * K_CAT + s1 * 8;
    const __hip_bfloat16* gB0 = B + (size_t)(tn * 256 + r0) * K_CAT + s0 * 8;
    const __hip_bfloat16* gB1 = B + (size_t)(tn * 256 + r1) * K_CAT + s1 * 8;

#define ISSUE_A(buf_, kt_) do { \
        gld_lds16(gA0 + (kt_) * 32, &smem[buf_][0][c0 * 8]); \
        gld_lds16(gA1 + (kt_) * 32, &smem[buf_][0][c1 * 8]); } while (0)
#define ISSUE_B(buf_, kt_) do { \
        gld_lds16(gB0 + (kt_) * 32, &smem[buf_][1][c0 * 8]); \
        gld_lds16(gB1 + (kt_) * 32, &smem[buf_][1][c1 * 8]); } while (0)

    // --- fragment read offsets (bf16 elements), swizzled k-slot ---
    // mfma_32x32x16: A row = lane&31, k = (lane>>5)*8 + j  (16B per lane)
    const int wid = t >> 6, lane = t & 63;
    const int wmb = (wid >> 2) * 128;   // wave M base within tile (4 frags of 32)
    const int wnb = (wid & 3) * 64;     // wave N base within tile (2 frags of 32)
    const int l31 = lane & 31, lh = lane >> 5;
    int offA[4][2], offB[2][2];
#pragma unroll
    for (int fm = 0; fm < 4; ++fm) {
        const int r = wmb + fm * 32 + l31;
#pragma unroll
        for (int ks = 0; ks < 2; ++ks) {
            const int slot = 2 * ks + lh;
            offA[fm][ks] = r * 32 + (slot ^ ((r >> 1) & 3)) * 8;
        }
    }
#pragma unroll
    for (int fn = 0; fn < 2; ++fn) {
        const int r = wnb + fn * 32 + l31;
#pragma unroll
        for (int ks = 0; ks < 2; ++ks) {
            const int slot = 2 * ks + lh;
            offB[fn][ks] = r * 32 + (slot ^ ((r >> 1) & 3)) * 8;
        }
    }

    f32x16 acc[4][2] = {};

    // --- prologue: stage tiles 0,1,2 into bufs 0,1,2 (12 loads/thread) ---
    ISSUE_A(0, 0); ISSUE_B(0, 0);
    ISSUE_A(1, 1); ISSUE_B(1, 1);
    ISSUE_A(2, 2); ISSUE_B(2, 2);
    asm volatile("s_waitcnt vmcnt(16)" ::: "memory");   // tile 0 landed
    __builtin_amdgcn_s_barrier();
    __builtin_amdgcn_sched_barrier(0);

    // --- main loop: 64 K-tiles, single barrier per kt, two k-slices ---
#pragma unroll 4
    for (int kt = 0; kt < NT; ++kt) {
        const int buf  = kt & 3;
        const int pf   = (kt < NT - 3) ? kt + 3 : NT - 1;  // clamped dummy prefetch
        const int pbuf = (kt + 3) & 3;                     // provably-dead buffer

        short8 a0[4], a1[4], b0[2], b1[2];
        // --- ks=0 frag reads (6 DS ops, oldest group) ---
#pragma unroll
        for (int fm = 0; fm < 4; ++fm) a0[fm] = *(const short8*)&smem[buf][0][offA[fm][0]];
#pragma unroll
        for (int fn = 0; fn < 2; ++fn) b0[fn] = *(const short8*)&smem[buf][1][offB[fn][0]];
        __builtin_amdgcn_sched_barrier(0);   // pin group order for counted lgkmcnt
        // --- ks=1 frag reads (6 DS ops) + prefetch issue ---
#pragma unroll
        for (int fm = 0; fm < 4; ++fm) a1[fm] = *(const short8*)&smem[buf][0][offA[fm][1]];
#pragma unroll
        for (int fn = 0; fn < 2; ++fn) b1[fn] = *(const short8*)&smem[buf][1][offB[fn][1]];
        ISSUE_A(pbuf, pf);
        ISSUE_B(pbuf, pf);
        __builtin_amdgcn_sched_barrier(0);
        asm volatile("s_waitcnt lgkmcnt(6)" ::: "memory");  // ks=0 frags landed
        __builtin_amdgcn_sched_barrier(0);
        __builtin_amdgcn_s_setprio(1);
#pragma unroll
        for (int fm = 0; fm < 4; ++fm)
#pragma unroll
            for (int fn = 0; fn < 2; ++fn)
                acc[fm][fn] = __builtin_amdgcn_mfma_f32_32x32x16_bf16(
                    a0[fm], b0[fn], acc[fm][fn], 0, 0, 0);
        __builtin_amdgcn_s_setprio(0);
        __builtin_amdgcn_sched_barrier(0);
        asm volatile("s_waitcnt lgkmcnt(0)" ::: "memory");  // ks=1 frags landed
        __builtin_amdgcn_sched_barrier(0);
        __builtin_amdgcn_s_setprio(1);
#pragma unroll
        for (int fm = 0; fm < 4; ++fm)
#pragma unroll
            for (int fn = 0; fn < 2; ++fn)
                acc[fm][fn] = __builtin_amdgcn_mfma_f32_32x32x16_bf16(
                    a1[fm], b1[fn], acc[fm][fn], 0, 0, 0);
        __builtin_amdgcn_s_setprio(0);
        __builtin_amdgcn_sched_barrier(0);
        // wait only for tile kt+1; tiles kt+2,kt+3 (16 loads) stay in flight.
        asm volatile("s_waitcnt vmcnt(16)" ::: "memory");
        __builtin_amdgcn_s_barrier();
        __builtin_amdgcn_sched_barrier(0);
    }
#undef ISSUE_A
#undef ISSUE_B

    // --- epilogue: 32x32 C/D layout: col=lane&31, row=(reg&3)+8*(reg>>2)+4*(lane>>5)
#pragma unroll
    for (int fn = 0; fn < 2; ++fn) {
        const int gn = tn * 256 + wnb + fn * 32 + l31;
        const float tsv = ts[gn];
        const float mv  = mcm[gn];
#pragma unroll
        for (int fm = 0; fm < 4; ++fm) {
            const int gm0 = tm * 256 + wmb + fm * 32 + lh * 4;
#pragma unroll
            for (int reg = 0; reg < 16; ++reg) {
                const int row = (reg & 3) + 8 * (reg >> 2);
                out[(size_t)(gm0 + row) * OUT_F + gn] = tsv * __expf(acc[fm][fn][reg] - mv);
            }
        }
    }
}

// ---------------------------------------------------------------------------
extern "C" void kernel_launch(void* const* d_in, const int* in_sizes, int n_in,
                              void* d_out, int out_size, void* d_ws, size_t ws_size,
                              hipStream_t stream) {
    const float* z     = (const float*)d_in[0];   // (16384,1024)
    const float* diag  = (const float*)d_in[1];   // (2048,1024)
    const float* mean  = (const float*)d_in[2];   // (2048,1024,1)
    const float* scale = (const float*)d_in[3];   // (2048,)
    float* out = (float*)d_out;                   // (16384,2048)

    char* ws = (char*)d_ws;
    const size_t A_BYTES = (size_t)M_DIM * K_CAT * sizeof(__hip_bfloat16);  // 67.1 MB
    const size_t B_BYTES = (size_t)OUT_F * K_CAT * sizeof(__hip_bfloat16);  //  8.4 MB
    __hip_bfloat16* Abuf = (__hip_bfloat16*)ws;
    __hip_bfloat16* Bbuf = (__hip_bfloat16*)(ws + A_BYTES);
    float* mcm = (float*)(ws + A_BYTES + B_BYTES);
    float* ts  = (float*)(ws + A_BYTES + B_BYTES + 8192);

    prep_z_kernel<<<(M_DIM * IN_F / 8) / 256, 256, 0, stream>>>(z, Abuf);
    prep_b_kernel<<<OUT_F, 256, 0, stream>>>(diag, mean, scale, Bbuf, mcm, ts);
    gemm_exp_kernel<<<(M_DIM / 256) * (OUT_F / 256), 512, 0, stream>>>(
        Abuf, Bbuf, mcm, ts, out);
}